// Round 1
// baseline (1206.623 us; speedup 1.0000x reference)
//
#include <hip/hip_runtime.h>
#include <math.h>

#define NPOS 196
#define NH 4
#define KD 16
#define DV 64
#define CHD 64
#define QKVO 96
#define DIM 256

// ---------------------------------------------------------------------------
// Kernel 0: transpose proj_w (256x256) -> wT[c][o] so kernel 2 loads coalesce.
// ---------------------------------------------------------------------------
__global__ void cga_tw(const float* __restrict__ pw, float* __restrict__ wT) {
    int c = blockIdx.x;
    int o = threadIdx.x;
    wT[c * DIM + o] = pw[o * DIM + c];
}

// ---------------------------------------------------------------------------
// Kernel 1: fused cascaded attention. One block per batch element.
// thread t < 196 owns spatial column n. feat[64] lives in registers.
// LDS: k_t[196][16] | v_t[196][64] (q[16][196] aliases v_t) | bias[196]
// ---------------------------------------------------------------------------
__global__ __launch_bounds__(256, 2) void cga_main(
    const float* __restrict__ x,      // (512,256,196)
    const float* __restrict__ qkv_w,  // (4,96,64)
    const float* __restrict__ qkv_s,  // (4,96)
    const float* __restrict__ qkv_b,  // (4,96)
    const float* __restrict__ dw_w,   // (4,16,25)
    const float* __restrict__ dw_s,   // (4,16)
    const float* __restrict__ dw_b,   // (4,16)
    const float* __restrict__ ab,     // (4,196)
    float* __restrict__ cat)          // (512,256,196)
{
    __shared__ float smem[3136 + 12544 + 196];  // 63504 B
    float* kt = smem;                  // [196][16]
    float* vt = smem + 3136;           // [196][64]
    float* ql = vt;                    // alias: q [16][196] (3136 floats)
    float* bl = smem + 3136 + 12544;   // [196]

    const int t = threadIdx.x;
    const int b = blockIdx.x;
    const bool act = t < NPOS;
    const int n = act ? t : (NPOS - 1);
    const int rn = n / 14;
    const int cn = n - rn * 14;

    const float* xb = x + (size_t)b * (DIM * NPOS);

    float feat[CHD];
#pragma unroll
    for (int c = 0; c < CHD; ++c) feat[c] = xb[c * NPOS + n];

#pragma unroll 1
    for (int i = 0; i < NH; ++i) {
        const float* w  = qkv_w + i * (QKVO * CHD);
        const float* sc = qkv_s + i * QKVO;
        const float* bi = qkv_b + i * QKVO;

        if (t < NPOS) bl[t] = ab[i * NPOS + t];

        // ---- phase 1a: q (o=0..15) and k (o=16..31) ----
#pragma unroll 1
        for (int o4 = 0; o4 < 8; ++o4) {
            const int ob = o4 * 4;
            const float* w0 = w + ob * CHD;
            float v0 = 0.f, v1 = 0.f, v2 = 0.f, v3 = 0.f;
#pragma unroll
            for (int c = 0; c < CHD; ++c) {
                float f = feat[c];
                v0 = fmaf(w0[c], f, v0);
                v1 = fmaf(w0[CHD + c], f, v1);
                v2 = fmaf(w0[2 * CHD + c], f, v2);
                v3 = fmaf(w0[3 * CHD + c], f, v3);
            }
            v0 = fmaf(v0, sc[ob + 0], bi[ob + 0]);
            v1 = fmaf(v1, sc[ob + 1], bi[ob + 1]);
            v2 = fmaf(v2, sc[ob + 2], bi[ob + 2]);
            v3 = fmaf(v3, sc[ob + 3], bi[ob + 3]);
            if (act) {
                if (o4 < 4) {  // q rows -> [ch][n] layout for the conv
                    ql[(ob + 0) * NPOS + n] = v0;
                    ql[(ob + 1) * NPOS + n] = v1;
                    ql[(ob + 2) * NPOS + n] = v2;
                    ql[(ob + 3) * NPOS + n] = v3;
                } else {       // k rows -> transposed [n][c]
                    *(float4*)&kt[n * KD + (ob - KD)] = make_float4(v0, v1, v2, v3);
                }
            }
        }
        __syncthreads();

        // ---- phase 2: 5x5 depthwise conv + affine + exact gelu + residual ----
        float q2[KD];
        {
            const float* dww = dw_w + i * (KD * 25);
            const float* dws = dw_s + i * KD;
            const float* dwb = dw_b + i * KD;
#pragma unroll
            for (int ch = 0; ch < KD; ++ch) {
                float s = 0.f;
#pragma unroll
                for (int kr = 0; kr < 5; ++kr) {
                    int rr = rn + kr - 2;
                    bool rok = (unsigned)rr < 14u;
#pragma unroll
                    for (int kc = 0; kc < 5; ++kc) {
                        int cc = cn + kc - 2;
                        bool ok = rok && ((unsigned)cc < 14u);
                        int idx = ok ? (rr * 14 + cc) : n;
                        float qv = ql[ch * NPOS + idx];
                        qv = ok ? qv : 0.f;
                        s = fmaf(qv, dww[ch * 25 + kr * 5 + kc], s);
                    }
                }
                float dv = fmaf(s, dws[ch], dwb[ch]);
                float g = 0.5f * dv * (1.f + erff(dv * 0.70710678118654752f));
                q2[ch] = g + ql[ch * NPOS + n];
            }
        }
        __syncthreads();  // conv reads of q done; safe to overwrite with v

        // ---- phase 3: v (o=32..95) -> v_t[n][d] ----
#pragma unroll 1
        for (int o4 = 0; o4 < 16; ++o4) {
            const int ob = 32 + o4 * 4;
            const float* w0 = w + ob * CHD;
            float v0 = 0.f, v1 = 0.f, v2 = 0.f, v3 = 0.f;
#pragma unroll
            for (int c = 0; c < CHD; ++c) {
                float f = feat[c];
                v0 = fmaf(w0[c], f, v0);
                v1 = fmaf(w0[CHD + c], f, v1);
                v2 = fmaf(w0[2 * CHD + c], f, v2);
                v3 = fmaf(w0[3 * CHD + c], f, v3);
            }
            v0 = fmaf(v0, sc[ob + 0], bi[ob + 0]);
            v1 = fmaf(v1, sc[ob + 1], bi[ob + 1]);
            v2 = fmaf(v2, sc[ob + 2], bi[ob + 2]);
            v3 = fmaf(v3, sc[ob + 3], bi[ob + 3]);
            if (act) *(float4*)&vt[n * DV + o4 * 4] = make_float4(v0, v1, v2, v3);
        }
        __syncthreads();

        // ---- phase 4: attention row n (no max-subtraction; logits small) ----
        float acc[DV];
#pragma unroll
        for (int d = 0; d < DV; ++d) acc[d] = 0.f;
        float den = 0.f;

#pragma unroll 1
        for (int rm = 0; rm < 14; ++rm) {
            int drr = (rn >= rm ? rn - rm : rm - rn) * 14;
#pragma unroll 1
            for (int cm = 0; cm < 14; ++cm) {
                int m = rm * 14 + cm;
                int idx = drr + (cn >= cm ? cn - cm : cm - cn);
                const float4* kf = (const float4*)&kt[m * KD];
                float4 k0 = kf[0], k1 = kf[1], k2 = kf[2], k3 = kf[3];
                float s = 0.f;
                s = fmaf(q2[0], k0.x, s);  s = fmaf(q2[1], k0.y, s);
                s = fmaf(q2[2], k0.z, s);  s = fmaf(q2[3], k0.w, s);
                s = fmaf(q2[4], k1.x, s);  s = fmaf(q2[5], k1.y, s);
                s = fmaf(q2[6], k1.z, s);  s = fmaf(q2[7], k1.w, s);
                s = fmaf(q2[8], k2.x, s);  s = fmaf(q2[9], k2.y, s);
                s = fmaf(q2[10], k2.z, s); s = fmaf(q2[11], k2.w, s);
                s = fmaf(q2[12], k3.x, s); s = fmaf(q2[13], k3.y, s);
                s = fmaf(q2[14], k3.z, s); s = fmaf(q2[15], k3.w, s);
                float logit = fmaf(s, 0.25f, bl[idx]);
                float p = __expf(logit);
                den += p;
                const float4* vf = (const float4*)&vt[m * DV];
#pragma unroll
                for (int d4 = 0; d4 < 16; ++d4) {
                    float4 v4 = vf[d4];
                    acc[d4 * 4 + 0] = fmaf(p, v4.x, acc[d4 * 4 + 0]);
                    acc[d4 * 4 + 1] = fmaf(p, v4.y, acc[d4 * 4 + 1]);
                    acc[d4 * 4 + 2] = fmaf(p, v4.z, acc[d4 * 4 + 2]);
                    acc[d4 * 4 + 3] = fmaf(p, v4.w, acc[d4 * 4 + 3]);
                }
            }
        }

        // ---- epilogue: normalize, relu->cat (global), feat = out + next x ----
        float inv = 1.f / den;
        float* cb = cat + ((size_t)b * DIM + i * DV) * NPOS;
        if (i < NH - 1) {
            const float* xn = xb + (i + 1) * CHD * NPOS;
#pragma unroll
            for (int d = 0; d < DV; ++d) {
                float val = acc[d] * inv;
                if (act) cb[d * NPOS + n] = fmaxf(val, 0.f);
                feat[d] = val + xn[d * NPOS + n];
            }
        } else {
#pragma unroll
            for (int d = 0; d < DV; ++d) {
                float val = acc[d] * inv;
                if (act) cb[d * NPOS + n] = fmaxf(val, 0.f);
            }
        }
        __syncthreads();  // protect LDS (kt/ql/vt/bl) before next head rewrites
    }
}

// ---------------------------------------------------------------------------
// Kernel 2: proj GEMM. Block = (b, n-chunk of 28). thread t = output channel.
// out[b,o,n] = ps[o]*sum_c wT[c][o]*cat[b,c,n] + pb[o]
// ---------------------------------------------------------------------------
__global__ __launch_bounds__(256, 4) void cga_proj(
    const float* __restrict__ cat, const float* __restrict__ wT,
    const float* __restrict__ ps, const float* __restrict__ pb,
    float* __restrict__ out)
{
    __shared__ float cl[DIM * 28];  // 28672 B
    const int t = threadIdx.x;
    const int b = blockIdx.x / 7;
    const int nc = blockIdx.x - b * 7;
    const int n0 = nc * 28;

    const float* cb = cat + (size_t)b * (DIM * NPOS) + n0;
    for (int idx = t; idx < DIM * 28; idx += 256) {
        int c = idx / 28;
        int j = idx - c * 28;
        cl[idx] = cb[c * NPOS + j];
    }
    __syncthreads();

    float acc[28];
#pragma unroll
    for (int j = 0; j < 28; ++j) acc[j] = 0.f;

    const float* wcol = wT + t;
#pragma unroll 4
    for (int c = 0; c < DIM; ++c) {
        float wv = wcol[c * DIM];
        const float4* cf = (const float4*)&cl[c * 28];
#pragma unroll
        for (int j4 = 0; j4 < 7; ++j4) {
            float4 cv = cf[j4];
            acc[j4 * 4 + 0] = fmaf(wv, cv.x, acc[j4 * 4 + 0]);
            acc[j4 * 4 + 1] = fmaf(wv, cv.y, acc[j4 * 4 + 1]);
            acc[j4 * 4 + 2] = fmaf(wv, cv.z, acc[j4 * 4 + 2]);
            acc[j4 * 4 + 3] = fmaf(wv, cv.w, acc[j4 * 4 + 3]);
        }
    }

    float s = ps[t];
    float bb = pb[t];
    float* ob = out + ((size_t)b * DIM + t) * NPOS + n0;
#pragma unroll
    for (int j = 0; j < 28; ++j) ob[j] = fmaf(acc[j], s, bb);
}

extern "C" void kernel_launch(void* const* d_in, const int* in_sizes, int n_in,
                              void* d_out, int out_size, void* d_ws, size_t ws_size,
                              hipStream_t stream) {
    const float* x      = (const float*)d_in[0];
    const float* qkv_w  = (const float*)d_in[1];
    const float* qkv_s  = (const float*)d_in[2];
    const float* qkv_b  = (const float*)d_in[3];
    const float* dw_w   = (const float*)d_in[4];
    const float* dw_s   = (const float*)d_in[5];
    const float* dw_b   = (const float*)d_in[6];
    const float* proj_w = (const float*)d_in[7];
    const float* proj_s = (const float*)d_in[8];
    const float* proj_b = (const float*)d_in[9];
    const float* ab     = (const float*)d_in[10];
    float* out = (float*)d_out;

    float* wT  = (float*)d_ws;                 // 256*256 floats
    float* cat = (float*)d_ws + DIM * DIM;     // 512*256*196 floats

    cga_tw<<<DIM, DIM, 0, stream>>>(proj_w, wT);
    cga_main<<<512, 256, 0, stream>>>(x, qkv_w, qkv_s, qkv_b,
                                      dw_w, dw_s, dw_b, ab, cat);
    cga_proj<<<512 * 7, 256, 0, stream>>>(cat, wT, proj_s, proj_b, out);
}

// Round 2
// 1146.553 us; speedup vs baseline: 1.0524x; 1.0524x over previous
//
#include <hip/hip_runtime.h>
#include <math.h>

#define NPOS 196
#define NH 4
#define KD 16
#define DV 64
#define CHD 64
#define QKVO 96
#define DIM 256

// ---------------------------------------------------------------------------
// Kernel 0: transpose proj_w (256x256) -> wT[c][o] so kernel 2 loads coalesce.
// ---------------------------------------------------------------------------
__global__ void cga_tw(const float* __restrict__ pw, float* __restrict__ wT) {
    int c = blockIdx.x;
    int o = threadIdx.x;
    wT[c * DIM + o] = pw[o * DIM + c];
}

// ---------------------------------------------------------------------------
// Kernel 1: fused cascaded attention. One block per batch element.
// thread t < 196 owns spatial column n. feat[64] lives in registers.
// LDS: kt[196][16] (xor-swizzled chunks) | vt[196][64] (xor-swizzled chunks,
//      aliased by ql[16][196] during phase 1/2) | bl[196]
// ---------------------------------------------------------------------------
__global__ __launch_bounds__(256, 2) void cga_main(
    const float* __restrict__ x,      // (512,256,196)
    const float* __restrict__ qkv_w,  // (4,96,64)
    const float* __restrict__ qkv_s,  // (4,96)
    const float* __restrict__ qkv_b,  // (4,96)
    const float* __restrict__ dw_w,   // (4,16,25)
    const float* __restrict__ dw_s,   // (4,16)
    const float* __restrict__ dw_b,   // (4,16)
    const float* __restrict__ ab,     // (4,196)
    float* __restrict__ cat)          // (512,256,196)
{
    __shared__ float smem[3136 + 12544 + 196];  // 63504 B -> 2 blocks/CU
    float* kt = smem;                  // [196][16], chunk c4 at (c4 ^ (n&3))
    float* vt = smem + 3136;           // [196][64], chunk d4 at (d4 ^ (n&15))
    float* ql = vt;                    // alias: q [16][196] (3136 floats)
    float* bl = smem + 3136 + 12544;   // [196]

    const int t = threadIdx.x;
    const int b = blockIdx.x;
    const bool act = t < NPOS;
    const int n = act ? t : (NPOS - 1);
    const int rn = n / 14;
    const int cn = n - rn * 14;

    const float* xb = x + (size_t)b * (DIM * NPOS);

    float feat[CHD];
#pragma unroll
    for (int c = 0; c < CHD; ++c) feat[c] = xb[c * NPOS + n];

#pragma unroll 1
    for (int i = 0; i < NH; ++i) {
        const float* w  = qkv_w + i * (QKVO * CHD);
        const float* sc = qkv_s + i * QKVO;
        const float* bi = qkv_b + i * QKVO;

        if (t < NPOS) bl[t] = ab[i * NPOS + t];

        // ---- phase 1: q (o=0..15) and k (o=16..31), 8 outputs per c-sweep --
#pragma unroll 1
        for (int o8 = 0; o8 < 4; ++o8) {
            const int ob = o8 * 8;
            const float* w0 = w + ob * CHD;
            float s[8];
#pragma unroll
            for (int j = 0; j < 8; ++j) s[j] = 0.f;
#pragma unroll
            for (int c = 0; c < CHD; ++c) {
                float f = feat[c];
#pragma unroll
                for (int j = 0; j < 8; ++j) s[j] = fmaf(w0[j * CHD + c], f, s[j]);
            }
#pragma unroll
            for (int j = 0; j < 8; ++j) s[j] = fmaf(s[j], sc[ob + j], bi[ob + j]);
            if (act) {
                if (o8 < 2) {  // q rows -> [ch][n] layout for the conv
#pragma unroll
                    for (int j = 0; j < 8; ++j) ql[(ob + j) * NPOS + n] = s[j];
                } else {       // k rows -> [n][c] with xor-swizzled float4 chunks
                    const int c4a = (o8 - 2) * 2;
                    *(float4*)&kt[n * KD + ((c4a ^ (n & 3)) << 2)] =
                        make_float4(s[0], s[1], s[2], s[3]);
                    *(float4*)&kt[n * KD + (((c4a + 1) ^ (n & 3)) << 2)] =
                        make_float4(s[4], s[5], s[6], s[7]);
                }
            }
        }
        __syncthreads();

        // ---- phase 2: 5x5 depthwise conv + affine + exact gelu + residual --
        float q2[KD];
        {
            const float* dww = dw_w + i * (KD * 25);
            const float* dws = dw_s + i * KD;
            const float* dwb = dw_b + i * KD;
#pragma unroll
            for (int ch = 0; ch < KD; ++ch) {
                float s = 0.f;
#pragma unroll
                for (int kr = 0; kr < 5; ++kr) {
                    int rr = rn + kr - 2;
                    bool rok = (unsigned)rr < 14u;
#pragma unroll
                    for (int kc = 0; kc < 5; ++kc) {
                        int cc = cn + kc - 2;
                        bool ok = rok && ((unsigned)cc < 14u);
                        int idx = ok ? (rr * 14 + cc) : n;
                        float qv = ql[ch * NPOS + idx];
                        qv = ok ? qv : 0.f;
                        s = fmaf(qv, dww[ch * 25 + kr * 5 + kc], s);
                    }
                }
                float dv = fmaf(s, dws[ch], dwb[ch]);
                float g = 0.5f * dv * (1.f + erff(dv * 0.70710678118654752f));
                q2[ch] = g + ql[ch * NPOS + n];
            }
        }
        __syncthreads();  // conv reads of q done; safe to overwrite with v

        // ---- phase 3: v (o=32..95) -> vt[n][d] xor-swizzled, 8 per sweep ---
#pragma unroll 1
        for (int o8 = 0; o8 < 8; ++o8) {
            const int ob = 32 + o8 * 8;
            const float* w0 = w + ob * CHD;
            float s[8];
#pragma unroll
            for (int j = 0; j < 8; ++j) s[j] = 0.f;
#pragma unroll
            for (int c = 0; c < CHD; ++c) {
                float f = feat[c];
#pragma unroll
                for (int j = 0; j < 8; ++j) s[j] = fmaf(w0[j * CHD + c], f, s[j]);
            }
#pragma unroll
            for (int j = 0; j < 8; ++j) s[j] = fmaf(s[j], sc[ob + j], bi[ob + j]);
            if (act) {
                const int d4a = o8 * 2;
                *(float4*)&vt[n * DV + ((d4a ^ (n & 15)) << 2)] =
                    make_float4(s[0], s[1], s[2], s[3]);
                *(float4*)&vt[n * DV + (((d4a + 1) ^ (n & 15)) << 2)] =
                    make_float4(s[4], s[5], s[6], s[7]);
            }
        }
        __syncthreads();

        // ---- phase 4: attention row n; 2 m's in flight -------------------
        float acc[DV];
#pragma unroll
        for (int d = 0; d < DV; ++d) acc[d] = 0.f;
        float den = 0.f;

#pragma unroll 1
        for (int rm = 0; rm < 14; ++rm) {
            const int drr = (rn >= rm ? rn - rm : rm - rn) * 14;
            const int mrow = rm * 14;
            for (int cmp = 0; cmp < 7; ++cmp) {
                const int cm0 = cmp * 2;
                const int m0 = mrow + cm0;
                const int m1 = m0 + 1;

                // k fragments (uniform-address broadcast, de-swizzle by m)
                const float4* kr0 = (const float4*)&kt[m0 * KD];
                const float4* kr1 = (const float4*)&kt[m1 * KD];
                const int t0 = m0 & 3, t1 = m1 & 3;
                float4 a0 = kr0[0 ^ t0], a1 = kr0[1 ^ t0],
                       a2 = kr0[2 ^ t0], a3 = kr0[3 ^ t0];
                float4 b0 = kr1[0 ^ t1], b1 = kr1[1 ^ t1],
                       b2 = kr1[2 ^ t1], b3 = kr1[3 ^ t1];

                // dual 4-way split dot products
                float s0a = fmaf(q2[1], a0.y, q2[0] * a0.x);
                s0a = fmaf(q2[2], a0.z, s0a); s0a = fmaf(q2[3], a0.w, s0a);
                float s0b = fmaf(q2[5], a1.y, q2[4] * a1.x);
                s0b = fmaf(q2[6], a1.z, s0b); s0b = fmaf(q2[7], a1.w, s0b);
                float s0c = fmaf(q2[9], a2.y, q2[8] * a2.x);
                s0c = fmaf(q2[10], a2.z, s0c); s0c = fmaf(q2[11], a2.w, s0c);
                float s0d = fmaf(q2[13], a3.y, q2[12] * a3.x);
                s0d = fmaf(q2[14], a3.z, s0d); s0d = fmaf(q2[15], a3.w, s0d);
                float dot0 = (s0a + s0b) + (s0c + s0d);

                float s1a = fmaf(q2[1], b0.y, q2[0] * b0.x);
                s1a = fmaf(q2[2], b0.z, s1a); s1a = fmaf(q2[3], b0.w, s1a);
                float s1b = fmaf(q2[5], b1.y, q2[4] * b1.x);
                s1b = fmaf(q2[6], b1.z, s1b); s1b = fmaf(q2[7], b1.w, s1b);
                float s1c = fmaf(q2[9], b2.y, q2[8] * b2.x);
                s1c = fmaf(q2[10], b2.z, s1c); s1c = fmaf(q2[11], b2.w, s1c);
                float s1d = fmaf(q2[13], b3.y, q2[12] * b3.x);
                s1d = fmaf(q2[14], b3.z, s1d); s1d = fmaf(q2[15], b3.w, s1d);
                float dot1 = (s1a + s1b) + (s1c + s1d);

                const int dc0 = cn >= cm0 ? cn - cm0 : cm0 - cn;
                const int dc1 = cn >= cm0 + 1 ? cn - cm0 - 1 : cm0 + 1 - cn;
                float p0 = __expf(fmaf(dot0, 0.25f, bl[drr + dc0]));
                float p1 = __expf(fmaf(dot1, 0.25f, bl[drr + dc1]));
                den += (p0 + p1);

                const float4* vr0 = (const float4*)&vt[m0 * DV];
                const float4* vr1 = (const float4*)&vt[m1 * DV];
                const int u0 = m0 & 15, u1 = m1 & 15;
#pragma unroll
                for (int d4 = 0; d4 < 16; ++d4) {
                    float4 v0 = vr0[d4 ^ u0];
                    float4 v1 = vr1[d4 ^ u1];
                    acc[d4 * 4 + 0] = fmaf(p0, v0.x, acc[d4 * 4 + 0]);
                    acc[d4 * 4 + 1] = fmaf(p0, v0.y, acc[d4 * 4 + 1]);
                    acc[d4 * 4 + 2] = fmaf(p0, v0.z, acc[d4 * 4 + 2]);
                    acc[d4 * 4 + 3] = fmaf(p0, v0.w, acc[d4 * 4 + 3]);
                    acc[d4 * 4 + 0] = fmaf(p1, v1.x, acc[d4 * 4 + 0]);
                    acc[d4 * 4 + 1] = fmaf(p1, v1.y, acc[d4 * 4 + 1]);
                    acc[d4 * 4 + 2] = fmaf(p1, v1.z, acc[d4 * 4 + 2]);
                    acc[d4 * 4 + 3] = fmaf(p1, v1.w, acc[d4 * 4 + 3]);
                }
            }
        }

        // ---- epilogue: normalize, relu->cat (global), feat = out + next x -
        float inv = 1.f / den;
        float* cb = cat + ((size_t)b * DIM + i * DV) * NPOS;
        if (i < NH - 1) {
            const float* xn = xb + (i + 1) * CHD * NPOS;
#pragma unroll
            for (int d = 0; d < DV; ++d) {
                float val = acc[d] * inv;
                if (act) cb[d * NPOS + n] = fmaxf(val, 0.f);
                feat[d] = val + xn[d * NPOS + n];
            }
        } else {
#pragma unroll
            for (int d = 0; d < DV; ++d) {
                float val = acc[d] * inv;
                if (act) cb[d * NPOS + n] = fmaxf(val, 0.f);
            }
        }
        __syncthreads();  // protect LDS (kt/ql/vt/bl) before next head rewrites
    }
}

// ---------------------------------------------------------------------------
// Kernel 2: proj GEMM. Block = (b, n-chunk of 28). thread t = output channel.
// out[b,o,n] = ps[o]*sum_c wT[c][o]*cat[b,c,n] + pb[o]
// Weight loads software-pipelined 8 deep.
// ---------------------------------------------------------------------------
__global__ __launch_bounds__(256, 5) void cga_proj(
    const float* __restrict__ cat, const float* __restrict__ wT,
    const float* __restrict__ ps, const float* __restrict__ pb,
    float* __restrict__ out)
{
    __shared__ float cl[DIM * 28];  // 28672 B -> 5 blocks/CU
    const int t = threadIdx.x;
    const int b = blockIdx.x / 7;
    const int nc = blockIdx.x - b * 7;
    const int n0 = nc * 28;

    const float* cb = cat + (size_t)b * (DIM * NPOS) + n0;
    // float4 staging: 256 rows x 7 float4
    for (int idx = t; idx < DIM * 7; idx += 256) {
        int c = idx / 7;
        int j = idx - c * 7;
        *(float4*)&cl[c * 28 + j * 4] = *(const float4*)&cb[c * NPOS + j * 4];
    }
    __syncthreads();

    float acc[28];
#pragma unroll
    for (int j = 0; j < 28; ++j) acc[j] = 0.f;

    const float* wcol = wT + t;
    float wv[8];
#pragma unroll
    for (int j = 0; j < 8; ++j) wv[j] = wcol[j * DIM];

#pragma unroll 1
    for (int c8 = 0; c8 < 32; ++c8) {
        float wn[8];
#pragma unroll
        for (int j = 0; j < 8; ++j)
            wn[j] = wcol[(((c8 * 8) + 8 + j) & 255) * DIM];
#pragma unroll
        for (int j = 0; j < 8; ++j) {
            float wvj = wv[j];
            const float4* cf = (const float4*)&cl[(c8 * 8 + j) * 28];
#pragma unroll
            for (int j4 = 0; j4 < 7; ++j4) {
                float4 cv = cf[j4];
                acc[j4 * 4 + 0] = fmaf(wvj, cv.x, acc[j4 * 4 + 0]);
                acc[j4 * 4 + 1] = fmaf(wvj, cv.y, acc[j4 * 4 + 1]);
                acc[j4 * 4 + 2] = fmaf(wvj, cv.z, acc[j4 * 4 + 2]);
                acc[j4 * 4 + 3] = fmaf(wvj, cv.w, acc[j4 * 4 + 3]);
            }
        }
#pragma unroll
        for (int j = 0; j < 8; ++j) wv[j] = wn[j];
    }

    float s = ps[t];
    float bb = pb[t];
    float* ob = out + ((size_t)b * DIM + t) * NPOS + n0;
#pragma unroll
    for (int j = 0; j < 28; ++j) ob[j] = fmaf(acc[j], s, bb);
}

extern "C" void kernel_launch(void* const* d_in, const int* in_sizes, int n_in,
                              void* d_out, int out_size, void* d_ws, size_t ws_size,
                              hipStream_t stream) {
    const float* x      = (const float*)d_in[0];
    const float* qkv_w  = (const float*)d_in[1];
    const float* qkv_s  = (const float*)d_in[2];
    const float* qkv_b  = (const float*)d_in[3];
    const float* dw_w   = (const float*)d_in[4];
    const float* dw_s   = (const float*)d_in[5];
    const float* dw_b   = (const float*)d_in[6];
    const float* proj_w = (const float*)d_in[7];
    const float* proj_s = (const float*)d_in[8];
    const float* proj_b = (const float*)d_in[9];
    const float* ab     = (const float*)d_in[10];
    float* out = (float*)d_out;

    float* wT  = (float*)d_ws;                 // 256*256 floats
    float* cat = (float*)d_ws + DIM * DIM;     // 512*256*196 floats

    cga_tw<<<DIM, DIM, 0, stream>>>(proj_w, wT);
    cga_main<<<512, 256, 0, stream>>>(x, qkv_w, qkv_s, qkv_b,
                                      dw_w, dw_s, dw_b, ab, cat);
    cga_proj<<<512 * 7, 256, 0, stream>>>(cat, wT, proj_s, proj_b, out);
}

// Round 4
// 926.653 us; speedup vs baseline: 1.3021x; 1.2373x over previous
//
#include <hip/hip_runtime.h>
#include <math.h>

typedef _Float16 h2 __attribute__((ext_vector_type(2)));

#define NPOS 196
#define NH 4
#define KD 16
#define DV 64
#define DIM 256

static __device__ __forceinline__ float fdot2(h2 a, h2 b, float c) {
#if __has_builtin(__builtin_amdgcn_fdot2)
    return __builtin_amdgcn_fdot2(a, b, c, false);
#else
    return fmaf((float)a.x, (float)b.x, fmaf((float)a.y, (float)b.y, c));
#endif
}
static __device__ __forceinline__ h2 pk(float a, float b) {  // RTE pack
    h2 r; r.x = (_Float16)a; r.y = (_Float16)b; return r;
}
static __device__ __forceinline__ h2 pkz(float a, float b) { // RTZ pack (hot path)
#if __has_builtin(__builtin_amdgcn_cvt_pkrtz)
    return __builtin_bit_cast(h2, __builtin_amdgcn_cvt_pkrtz(a, b));
#else
    return pk(a, b);
#endif
}
union fhu { float f; h2 h; };
static __device__ __forceinline__ h2 as_h2(float f) { fhu u; u.f = f; return u.h; }
static __device__ __forceinline__ float as_f(h2 h) { fhu u; u.h = h; return u.f; }

// ---------------------------------------------------------------------------
// Kernel 0: pack proj_w -> wh2[c2][o] (half2 over c-pairs) and
//           qkv_w -> qw2[(i*96+o)][c2] (half2 over c-pairs).
// ---------------------------------------------------------------------------
__global__ void cga_prep(const float* __restrict__ pw, const float* __restrict__ qw,
                         h2* __restrict__ wh2, h2* __restrict__ qw2) {
    const int bid = blockIdx.x, t = threadIdx.x;
    if (bid < 128) {
        const int c2 = bid, o = t;
        wh2[c2 * DIM + o] = pk(pw[o * DIM + 2 * c2], pw[o * DIM + 2 * c2 + 1]);
    } else {
        const int idx = (bid - 128) * 256 + t;  // 0..12287 = 384*32
        const int c2 = idx & 31, oo = idx >> 5;
        qw2[idx] = pk(qw[oo * 64 + 2 * c2], qw[oo * 64 + 2 * c2 + 1]);
    }
}

// ---------------------------------------------------------------------------
// Kernel 1: fused cascaded attention, fp16 storage + v_dot2_f32_f16 compute.
// One block per batch. thread t<196 owns position n. feat in 32 half2 regs.
// LDS bytes: kt half[196][16]  [0,6272)
//            vtp 98 rows x 64 half2 (m-pair interleaved, 16B-chunk XOR
//                swizzled by mp&15) [6272,31360); ql fp32[16][196] aliases it
//            bl fp32[196] [31360,32144)
// ---------------------------------------------------------------------------
__global__ __launch_bounds__(256, 4) void cga_main(
    const float* __restrict__ x,      // (512,256,196)
    const h2*    __restrict__ qw2,    // (4,96,32) half2
    const float* __restrict__ qkv_s,  // (4,96)
    const float* __restrict__ qkv_b,  // (4,96)
    const float* __restrict__ dw_w,   // (4,16,25)
    const float* __restrict__ dw_s,   // (4,16)
    const float* __restrict__ dw_b,   // (4,16)
    const float* __restrict__ ab,     // (4,196)
    h2* __restrict__ catI)            // (512,128,196) half2 over c-pairs
{
    __shared__ __align__(16) char smem[32144];
    char* vtpB = smem + 6272;
    float* ql  = (float*)(smem + 6272);
    float* bl  = (float*)(smem + 31360);

    const int t = threadIdx.x;
    const int b = blockIdx.x;
    const bool act = t < NPOS;
    const int n = act ? t : (NPOS - 1);
    const int rn = n / 14;
    const int cn = n - rn * 14;

    const float* xb = x + (size_t)b * (DIM * NPOS);

    h2 feat2[32];
#pragma unroll
    for (int e = 0; e < 32; ++e)
        feat2[e] = pk(xb[(2 * e) * NPOS + n], xb[(2 * e + 1) * NPOS + n]);

#pragma unroll 1
    for (int i = 0; i < NH; ++i) {
        const h2* w2   = qw2 + i * (96 * 32);
        const float* sc = qkv_s + i * 96;
        const float* bi = qkv_b + i * 96;

        if (t < NPOS) bl[t] = ab[i * NPOS + t] - 4.0f;  // shift: softmax-invariant

        // ---- phase 1: q (o 0..15) -> ql fp32; k (o 16..31) -> kt fp16 -----
#pragma unroll 1
        for (int o8 = 0; o8 < 4; ++o8) {
            const int ob = o8 * 8;
            const h2* w0 = w2 + ob * 32;
            float s[8];
#pragma unroll
            for (int j = 0; j < 8; ++j) s[j] = 0.f;
#pragma unroll
            for (int c2 = 0; c2 < 32; ++c2) {
                h2 f = feat2[c2];
#pragma unroll
                for (int j = 0; j < 8; ++j) s[j] = fdot2(f, w0[j * 32 + c2], s[j]);
            }
#pragma unroll
            for (int j = 0; j < 8; ++j) s[j] = fmaf(s[j], sc[ob + j], bi[ob + j]);
            if (act) {
                if (o8 < 2) {
#pragma unroll
                    for (int j = 0; j < 8; ++j) ql[(ob + j) * NPOS + n] = s[j];
                } else {
                    float4 kw;
                    kw.x = as_f(pk(s[0], s[1]));
                    kw.y = as_f(pk(s[2], s[3]));
                    kw.z = as_f(pk(s[4], s[5]));
                    kw.w = as_f(pk(s[6], s[7]));
                    *(float4*)(smem + n * 32 + (o8 - 2) * 16) = kw;
                }
            }
        }
        __syncthreads();

        // ---- phase 2: 5x5 depthwise conv + affine + exact gelu + residual -
        h2 q2h[8];
        {
            const float* dww = dw_w + i * (KD * 25);
            const float* dws = dw_s + i * KD;
            const float* dwb = dw_b + i * KD;
            float q2[KD];
#pragma unroll
            for (int ch = 0; ch < KD; ++ch) {
                float s = 0.f;
#pragma unroll
                for (int kr = 0; kr < 5; ++kr) {
                    int rr = rn + kr - 2;
                    bool rok = (unsigned)rr < 14u;
#pragma unroll
                    for (int kc = 0; kc < 5; ++kc) {
                        int cc = cn + kc - 2;
                        bool ok = rok && ((unsigned)cc < 14u);
                        int idx = ok ? (rr * 14 + cc) : n;
                        float qv = ql[ch * NPOS + idx];
                        qv = ok ? qv : 0.f;
                        s = fmaf(qv, dww[ch * 25 + kr * 5 + kc], s);
                    }
                }
                float dv = fmaf(s, dws[ch], dwb[ch]);
                float g = 0.5f * dv * (1.f + erff(dv * 0.70710678118654752f));
                q2[ch] = g + ql[ch * NPOS + n];
            }
#pragma unroll
            for (int e = 0; e < 8; ++e) q2h[e] = pk(q2[2 * e], q2[2 * e + 1]);
        }
        __syncthreads();  // conv reads done; vtp may overwrite ql region

        // ---- phase 3: v (o 32..95) -> vtp m-pair-interleaved fp16 ---------
#pragma unroll 1
        for (int o8 = 0; o8 < 8; ++o8) {
            const int ob = 32 + o8 * 8;
            const h2* w0 = w2 + ob * 32;
            float s[8];
#pragma unroll
            for (int j = 0; j < 8; ++j) s[j] = 0.f;
#pragma unroll
            for (int c2 = 0; c2 < 32; ++c2) {
                h2 f = feat2[c2];
#pragma unroll
                for (int j = 0; j < 8; ++j) s[j] = fdot2(f, w0[j * 32 + c2], s[j]);
            }
#pragma unroll
            for (int j = 0; j < 8; ++j) s[j] = fmaf(s[j], sc[ob + j], bi[ob + j]);

            float sp[8];
#pragma unroll
            for (int j = 0; j < 8; ++j) sp[j] = __shfl_xor(s[j], 1, 64);
            const int par = t & 1;
            float4 vw;
            if (par == 0) {  // lane holds m0: (own, partner)
                vw.x = as_f(pk(s[0], sp[0])); vw.y = as_f(pk(s[1], sp[1]));
                vw.z = as_f(pk(s[2], sp[2])); vw.w = as_f(pk(s[3], sp[3]));
            } else {         // lane holds m1: (partner, own)
                vw.x = as_f(pk(sp[4], s[4])); vw.y = as_f(pk(sp[5], s[5]));
                vw.z = as_f(pk(sp[6], s[6])); vw.w = as_f(pk(sp[7], s[7]));
            }
            if (act) {
                const int mp = n >> 1;
                const int g = 2 * o8 + par;  // 16B chunk: d-pairs 4g..4g+3
                *(float4*)(vtpB + mp * 256 + ((g ^ (mp & 15)) << 4)) = vw;
            }
        }
        __syncthreads();

        // ---- phase 4: attention row n, fdot2 over m-pairs -----------------
        float acc[DV];
#pragma unroll
        for (int d = 0; d < DV; ++d) acc[d] = 0.f;
        float den = 0.f;

#pragma unroll 1
        for (int rm = 0; rm < 14; ++rm) {
            const int drr = (rn >= rm ? rn - rm : rm - rn) * 14;
            const int mrow = rm * 14;
            for (int cmp = 0; cmp < 7; ++cmp) {
                const int m0 = mrow + 2 * cmp;
                const int mp = m0 >> 1;
                const float4* kr0 = (const float4*)(smem + m0 * 32);
                float4 ka = kr0[0], kb = kr0[1];
                const float4* kr1 = (const float4*)(smem + m0 * 32 + 32);
                float4 kc = kr1[0], kd = kr1[1];

                float s0a = fdot2(q2h[0], as_h2(ka.x), 0.f);
                s0a = fdot2(q2h[1], as_h2(ka.y), s0a);
                s0a = fdot2(q2h[2], as_h2(ka.z), s0a);
                s0a = fdot2(q2h[3], as_h2(ka.w), s0a);
                float s0b = fdot2(q2h[4], as_h2(kb.x), 0.f);
                s0b = fdot2(q2h[5], as_h2(kb.y), s0b);
                s0b = fdot2(q2h[6], as_h2(kb.z), s0b);
                s0b = fdot2(q2h[7], as_h2(kb.w), s0b);
                float s1a = fdot2(q2h[0], as_h2(kc.x), 0.f);
                s1a = fdot2(q2h[1], as_h2(kc.y), s1a);
                s1a = fdot2(q2h[2], as_h2(kc.z), s1a);
                s1a = fdot2(q2h[3], as_h2(kc.w), s1a);
                float s1b = fdot2(q2h[4], as_h2(kd.x), 0.f);
                s1b = fdot2(q2h[5], as_h2(kd.y), s1b);
                s1b = fdot2(q2h[6], as_h2(kd.z), s1b);
                s1b = fdot2(q2h[7], as_h2(kd.w), s1b);

                const int cm0 = 2 * cmp, cm1 = cm0 + 1;
                const int dc0 = cn >= cm0 ? cn - cm0 : cm0 - cn;
                const int dc1 = cn >= cm1 ? cn - cm1 : cm1 - cn;
                float p0 = __expf(fmaf(s0a + s0b, 0.25f, bl[drr + dc0]));
                float p1 = __expf(fmaf(s1a + s1b, 0.25f, bl[drr + dc1]));
                den += p0 + p1;
                h2 ph = pkz(p0, p1);

                const char* vrow = vtpB + mp * 256;
                const int sw = mp & 15;
#pragma unroll
                for (int g = 0; g < 16; ++g) {
                    float4 vv = *(const float4*)(vrow + ((g ^ sw) << 4));
                    acc[4 * g + 0] = fdot2(ph, as_h2(vv.x), acc[4 * g + 0]);
                    acc[4 * g + 1] = fdot2(ph, as_h2(vv.y), acc[4 * g + 1]);
                    acc[4 * g + 2] = fdot2(ph, as_h2(vv.z), acc[4 * g + 2]);
                    acc[4 * g + 3] = fdot2(ph, as_h2(vv.w), acc[4 * g + 3]);
                }
            }
        }

        // ---- epilogue: normalize, relu -> catI (half2), feat = out + x ----
        float inv = 1.f / den;
        h2* cb = catI + ((size_t)b * 128 + i * 32) * NPOS;
        if (i < NH - 1) {
            const float* xn = xb + (i + 1) * 64 * NPOS;
#pragma unroll
            for (int e = 0; e < 32; ++e) {
                float v0 = acc[2 * e] * inv, v1 = acc[2 * e + 1] * inv;
                if (act) cb[e * NPOS + n] = pk(fmaxf(v0, 0.f), fmaxf(v1, 0.f));
                feat2[e] = pk(v0 + xn[(2 * e) * NPOS + n],
                              v1 + xn[(2 * e + 1) * NPOS + n]);
            }
        } else {
#pragma unroll
            for (int e = 0; e < 32; ++e) {
                float v0 = acc[2 * e] * inv, v1 = acc[2 * e + 1] * inv;
                if (act) cb[e * NPOS + n] = pk(fmaxf(v0, 0.f), fmaxf(v1, 0.f));
            }
        }
        __syncthreads();  // protect LDS before next head rewrites
    }
}

// ---------------------------------------------------------------------------
// Kernel 2: proj GEMM via fdot2. Block = (b, 28-col chunk). thread = out chan.
// ---------------------------------------------------------------------------
__global__ __launch_bounds__(256, 4) void cga_proj(
    const h2* __restrict__ catI, const h2* __restrict__ wh2,
    const float* __restrict__ ps, const float* __restrict__ pb,
    float* __restrict__ out)
{
    __shared__ __align__(16) h2 cl[128 * 28];  // 14336 B
    const int t = threadIdx.x;
    const int b = blockIdx.x / 7;
    const int nc = blockIdx.x - b * 7;
    const int n0 = nc * 28;

    const h2* cb = catI + (size_t)b * (128 * NPOS) + n0;
    for (int idx = t; idx < 128 * 7; idx += 256) {
        int c2 = idx / 7;
        int j4 = idx - c2 * 7;
        *(float4*)&cl[c2 * 28 + j4 * 4] = *(const float4*)&cb[c2 * NPOS + j4 * 4];
    }
    __syncthreads();

    float acc[28];
#pragma unroll
    for (int j = 0; j < 28; ++j) acc[j] = 0.f;

    const h2* wcol = wh2 + t;
    h2 wv[8];
#pragma unroll
    for (int j = 0; j < 8; ++j) wv[j] = wcol[j * DIM];

#pragma unroll 1
    for (int c8 = 0; c8 < 16; ++c8) {
        h2 wn[8];
#pragma unroll
        for (int j = 0; j < 8; ++j)
            wn[j] = wcol[(((c8 * 8) + 8 + j) & 127) * DIM];
#pragma unroll
        for (int j = 0; j < 8; ++j) {
            h2 w = wv[j];
            const float4* cf = (const float4*)&cl[(c8 * 8 + j) * 28];
#pragma unroll
            for (int j4 = 0; j4 < 7; ++j4) {
                float4 cv = cf[j4];
                acc[j4 * 4 + 0] = fdot2(w, as_h2(cv.x), acc[j4 * 4 + 0]);
                acc[j4 * 4 + 1] = fdot2(w, as_h2(cv.y), acc[j4 * 4 + 1]);
                acc[j4 * 4 + 2] = fdot2(w, as_h2(cv.z), acc[j4 * 4 + 2]);
                acc[j4 * 4 + 3] = fdot2(w, as_h2(cv.w), acc[j4 * 4 + 3]);
            }
        }
#pragma unroll
        for (int j = 0; j < 8; ++j) wv[j] = wn[j];
    }

    float s = ps[t], bb = pb[t];
    float* ob = out + ((size_t)b * DIM + t) * NPOS + n0;
#pragma unroll
    for (int j = 0; j < 28; ++j) ob[j] = fmaf(acc[j], s, bb);
}

extern "C" void kernel_launch(void* const* d_in, const int* in_sizes, int n_in,
                              void* d_out, int out_size, void* d_ws, size_t ws_size,
                              hipStream_t stream) {
    const float* x      = (const float*)d_in[0];
    const float* qkv_w  = (const float*)d_in[1];
    const float* qkv_s  = (const float*)d_in[2];
    const float* qkv_b  = (const float*)d_in[3];
    const float* dw_w   = (const float*)d_in[4];
    const float* dw_s   = (const float*)d_in[5];
    const float* dw_b   = (const float*)d_in[6];
    const float* proj_w = (const float*)d_in[7];
    const float* proj_s = (const float*)d_in[8];
    const float* proj_b = (const float*)d_in[9];
    const float* ab     = (const float*)d_in[10];
    float* out = (float*)d_out;

    h2* wh2  = (h2*)d_ws;                          // 32768 h2 = 131072 B
    h2* qw2  = (h2*)((char*)d_ws + 131072);        // 12288 h2 = 49152 B
    h2* catI = (h2*)((char*)d_ws + 180224);        // 512*128*196 h2 = 51.4 MB

    cga_prep<<<176, 256, 0, stream>>>(proj_w, qkv_w, wh2, qw2);
    cga_main<<<512, 256, 0, stream>>>(x, qw2, qkv_s, qkv_b,
                                      dw_w, dw_s, dw_b, ab, catI);
    cga_proj<<<512 * 7, 256, 0, stream>>>(catI, wh2, proj_s, proj_b, out);
}